// Round 16
// baseline (299.537 us; speedup 1.0000x reference)
//
#include <hip/hip_runtime.h>
#include <hip/hip_cooperative_groups.h>

namespace cg = cooperative_groups;

#define ALPHA 0.2f

constexpr int WDIM = 128;
constexpr int KDIM = 1024;
constexpr int NSEG = 64;             // rank segments
constexpr int SEGLEN = KDIM / NSEG;  // 16
constexpr int NB = 32;

typedef _Float16 h4 __attribute__((ext_vector_type(4)));
typedef _Float16 h8 __attribute__((ext_vector_type(8)));

// per-batch workspace layout (float offsets). XTH = 1024*128 fp16 = 65536 floats.
constexpr int OFF_XTH  = 0;        // [1024][128] _Float16 xT (65536 floats)
constexpr int OFF_TABH = 65536;    // [1025][256] _Float16 within-seg partials
constexpr int OFF_ESC  = 196736;   // [1024] f32 exp(s2 - M2) sorted desc
constexpr int OFF_ESCA = 197760;   // [1024] f32 exp(alpha*s2) sorted
constexpr int OFF_ABT  = 198784;   // [1025][2] f32 (a(c), b(c)) pad->2176
constexpr int OFF_U    = 200960;   // [1024]
constexpr int OFF_T    = 201984;   // [1024]
constexpr int OFF_S1   = 203008;   // [1024]
constexpr int OFF_S2   = 204032;   // [1024]
constexpr int OFF_CC   = 205056;   // [1024] int: c_i
constexpr int OFF_PERM = 206080;   // [1024] int: perm[rank] = j
constexpr int OFF_TA   = 207104;   // [NSEG][128] segment totals (A)
constexpr int OFF_TB   = 215296;   // [NSEG][128] segment totals (B)
constexpr int OFF_SBA  = 223488;   // [NSEG][128] f32 base: sum of segs before
constexpr int OFF_SBB  = 231680;   // [NSEG][128] f32 base: sum of segs after
constexpr int PBF      = 239872;   // per-batch stride (floats) = 959 KB

// ============================ MEGAKERNEL =================================
// 512 blocks x 256 threads, cooperative. Stages separated by grid.sync().
__global__ __launch_bounds__(256) void k_mega(const float* __restrict__ x,
                                              const float* __restrict__ w,
                                              float* __restrict__ ws,
                                              float* __restrict__ out) {
  cg::grid_group gg = cg::this_grid();
  __shared__ __align__(16) char smem[8192];
  int t = threadIdx.x;
  int cb = blockIdx.x;  // 0..511

  // ---- Stage 1: s12 (512 vblocks; vb = slot*16 + bx) [R15 body] ----
  {
    int bx = cb & 15, slot = cb >> 4;
    float* base = ws + (size_t)slot * PBF;
    float* w1s = (float*)smem;                    // [128]
    float* w2s = w1s + 128;                       // [128]
    float* red1 = w2s + 128;                      // [4][64]
    float* red2 = red1 + 256;                     // [4][64]
    if (t < WDIM) { w1s[t] = w[t]; w2s[t] = w[WDIM + t]; }
    __syncthreads();
    int jj = t & 63, wg = t >> 6;
    int j = bx * 64 + jj;
    int w0 = wg * 32;
    const float* xb = x + (size_t)slot * (WDIM * KDIM);
    float s1 = 0.f, s2 = 0.f;
    float vals[32];
#pragma unroll
    for (int k = 0; k < 32; ++k) {
      float v = xb[(w0 + k) * KDIM + j];
      vals[k] = v;
      s1 = fmaf(v, w1s[w0 + k], s1);
      s2 = fmaf(v, w2s[w0 + k], s2);
    }
    _Float16* xrowh = (_Float16*)(base + OFF_XTH) + j * WDIM + w0;
#pragma unroll
    for (int q = 0; q < 4; ++q) {
      h8 hv;
#pragma unroll
      for (int e = 0; e < 8; ++e) hv[e] = (_Float16)vals[8 * q + e];
      *(h8*)(xrowh + 8 * q) = hv;
    }
    red1[wg * 64 + jj] = s1;
    red2[wg * 64 + jj] = s2;
    __syncthreads();
    if (wg == 0) {
      base[OFF_S1 + j] = red1[jj] + red1[64 + jj] + red1[128 + jj] + red1[192 + jj];
      base[OFF_S2 + j] = red2[jj] + red2[64 + jj] + red2[128 + jj] + red2[192 + jj];
    }
  }
  gg.sync();

  // ---- Stage 2: rank (512 vblocks; 64 j's each; 256-thread re-lane) ----
  {
    int bx = cb & 15, slot = cb >> 4;
    float* base = ws + (size_t)slot * PBF;
    float* s2s = (float*)smem;                    // [1024]
    float* red = s2s + 1024;                      // [256]
    int* prr = (int*)(red + 256);                 // [64][4]
    int* pcc = prr + 256;                         // [64][4]
    for (int i = t; i < KDIM; i += 256) s2s[i] = base[OFF_S2 + i];
    __syncthreads();
    red[t] = fmaxf(fmaxf(s2s[t], s2s[t + 256]), fmaxf(s2s[t + 512], s2s[t + 768]));
    __syncthreads();
    for (int s = 128; s > 0; s >>= 1) {
      if (t < s) red[t] = fmaxf(red[t], red[t + s]);
      __syncthreads();
    }
    float M2 = red[0];
    int jj = t >> 2, quarter = t & 3;
    int j = bx * 64 + jj;
    float s2me = s2s[j];
    float s1me = base[OFF_S1 + j];
    float key = -s1me;
    int r = 0, c = 0;
    int lo = quarter * 256;
#pragma unroll 4
    for (int k2 = 0; k2 < 256; ++k2) {
      float v = s2s[lo + k2];
      int jp = lo + k2;
      r += (v > s2me || (v == s2me && jp < j)) ? 1 : 0;
      c += (v >= key) ? 1 : 0;
    }
    prr[jj * 4 + quarter] = r;
    pcc[jj * 4 + quarter] = c;
    __syncthreads();
    if (quarter == 0) {
      int R = prr[jj * 4] + prr[jj * 4 + 1] + prr[jj * 4 + 2] + prr[jj * 4 + 3];
      int C = pcc[jj * 4] + pcc[jj * 4 + 1] + pcc[jj * 4 + 2] + pcc[jj * 4 + 3];
      ((int*)(base + OFF_CC))[j] = C;
      ((int*)(base + OFF_PERM))[R] = j;
      base[OFF_ESC + R] = __expf(s2me - M2);
      base[OFF_ESCA + R] = __expf(ALPHA * s2me);
      float z = s1me + M2;
      float mi = z >= 0.f ? z : ALPHA * z;
      base[OFF_U + j] = __expf(z - mi);
      base[OFF_T + j] = __expf(ALPHA * s1me - mi);
    }
  }
  gg.sync();

  // ---- Stage 3: scant (1024 vblocks of 2 segs; 2 iters/coop block) ----
  for (int it = 0; it < 2; ++it) {
    int vb = cb * 2 + it;                 // 0..1023
    int slot = vb >> 5;                   // 32 seg-pairs per batch
    int segpair = vb & 31;
    int sl = t >> 7, wl = t & 127;
    int seg = segpair * 2 + sl;
    float* base = ws + (size_t)slot * PBF;
    int r0 = seg * SEGLEN;
    const _Float16* xTh = (const _Float16*)(base + OFF_XTH);
    const int* prm = (const int*)(base + OFF_PERM);
    int pr16[SEGLEN];
#pragma unroll
    for (int k = 0; k < SEGLEN; ++k) pr16[k] = prm[r0 + k];
    float xv[SEGLEN], eav[SEGLEN], ebv[SEGLEN];
#pragma unroll
    for (int k = 0; k < SEGLEN; ++k) {
      xv[k] = (float)xTh[pr16[k] * WDIM + wl];
      eav[k] = base[OFF_ESC + r0 + k];
      ebv[k] = base[OFF_ESCA + r0 + k];
    }
    _Float16* TABh = (_Float16*)(base + OFF_TABH);
    float accA = 0.f;
#pragma unroll
    for (int k = 0; k < SEGLEN; ++k) {
      TABh[(r0 + k) * 256 + wl] = (_Float16)accA;
      accA = fmaf(eav[k], xv[k], accA);
    }
    base[OFF_TA + seg * WDIM + wl] = accA;
    if (seg == NSEG - 1) {
      TABh[KDIM * 256 + wl] = (_Float16)accA;
      TABh[KDIM * 256 + 128 + wl] = (_Float16)0.f;
    }
    float accB = 0.f;
#pragma unroll
    for (int k = SEGLEN - 1; k >= 0; --k) {
      accB = fmaf(ebv[k], xv[k], accB);
      TABh[(r0 + k) * 256 + 128 + wl] = (_Float16)accB;
    }
    base[OFF_TB + seg * WDIM + wl] = accB;
  }
  gg.sync();

  // ---- Stage 4: base (96 vblocks) [R15 body] ----
  if (cb < 96) {
    int slot = cb / 3;
    int bxx = cb % 3;
    float* base = ws + (size_t)slot * PBF;
    float* gA = (float*)smem;                     // [2][128]
    float* gB = gA + 256;                         // [2][128]
    float* sc = gB + 256;                         // [256]
    if (bxx == 0) {
      int w2 = t & 127, h = t >> 7;
      float ta32[32], tb32[32];
      float ga = 0.f, gb = 0.f;
#pragma unroll
      for (int k = 0; k < 32; ++k) {
        ta32[k] = base[OFF_TA + (h * 32 + k) * WDIM + w2];
        tb32[k] = base[OFF_TB + (h * 32 + k) * WDIM + w2];
        ga += ta32[k];
        gb += tb32[k];
      }
      gA[h * 128 + w2] = ga;
      gB[h * 128 + w2] = gb;
      __syncthreads();
      float bA = (h == 1) ? gA[w2] : 0.f;
      float bB = (h == 0) ? gB[128 + w2] : 0.f;
#pragma unroll
      for (int k = 0; k < 32; ++k) {
        base[OFF_SBA + (h * 32 + k) * WDIM + w2] = bA;
        bA += ta32[k];
      }
#pragma unroll
      for (int k = 31; k >= 0; --k) {
        base[OFF_SBB + (h * 32 + k) * WDIM + w2] = bB;
        bB += tb32[k];
      }
    } else if (bxx == 1) {
      float4 v = *(const float4*)(base + OFF_ESC + 4 * t);
      float p1 = v.x, p2 = p1 + v.y, p3 = p2 + v.z, p4 = p3 + v.w;
      sc[t] = p4;
      __syncthreads();
      for (int s = 1; s < 256; s <<= 1) {
        float add = (t >= s) ? sc[t - s] : 0.f;
        __syncthreads();
        sc[t] += add;
        __syncthreads();
      }
      float bs = (t > 0) ? sc[t - 1] : 0.f;
      float* ABT = base + OFF_ABT;
      ABT[2 * (4 * t + 1)] = bs + p1;
      ABT[2 * (4 * t + 2)] = bs + p2;
      ABT[2 * (4 * t + 3)] = bs + p3;
      ABT[2 * (4 * t + 4)] = bs + p4;
      if (t == 0) ABT[0] = 0.f;
    } else {
      float4 v = *(const float4*)(base + OFF_ESCA + 4 * t);
      float q3 = v.w, q2 = v.z + q3, q1 = v.y + q2, q0 = v.x + q1;
      sc[t] = q0;
      __syncthreads();
      for (int s = 1; s < 256; s <<= 1) {
        float add = (t + s < 256) ? sc[t + s] : 0.f;
        __syncthreads();
        sc[t] += add;
        __syncthreads();
      }
      float bs = (t < 255) ? sc[t + 1] : 0.f;
      float* ABT = base + OFF_ABT;
      ABT[2 * (4 * t + 0) + 1] = bs + q0;
      ABT[2 * (4 * t + 1) + 1] = bs + q1;
      ABT[2 * (4 * t + 2) + 1] = bs + q2;
      ABT[2 * (4 * t + 3) + 1] = bs + q3;
      if (t == 255) ABT[2 * KDIM + 1] = 0.f;
    }
  }
  gg.sync();

  // ---- Stage 5: out (4096 vblocks; 8 iters/coop block) [R15 body] ----
  for (int it = 0; it < 8; ++it) {
    int vb = cb * 8 + it;                 // 0..4095
    int slot = vb >> 7;                   // 128 vblocks per batch
    int obx = vb & 127;
    const float* base = ws + (size_t)slot * PBF;
    int q = obx * 256 + t;                // 0..32767
    int i = q >> 5;
    int wq = (q & 31) << 2;
    int c = ((const int*)(base + OFF_CC))[i];
    int seg = c >> 4; if (seg > NSEG - 1) seg = NSEG - 1;
    float u = base[OFF_U + i];
    float tt = base[OFF_T + i];
    float2 ab = *(const float2*)(base + OFF_ABT + 2 * c);
    float rden = 1.f / fmaf(u, ab.x, tt * ab.y);
    const _Float16* TABh = (const _Float16*)(base + OFF_TABH);
    h4 A4 = *(const h4*)(TABh + (size_t)c * 256 + wq);
    h4 B4 = *(const h4*)(TABh + (size_t)c * 256 + 128 + wq);
    float4 sa4 = *(const float4*)(base + OFF_SBA + seg * WDIM + wq);
    float4 sb4 = *(const float4*)(base + OFF_SBB + seg * WDIM + wq);
    float4 o;
    o.x = (u * (sa4.x + (float)A4[0]) + tt * (sb4.x + (float)B4[0])) * rden;
    o.y = (u * (sa4.y + (float)A4[1]) + tt * (sb4.y + (float)B4[1])) * rden;
    o.z = (u * (sa4.z + (float)A4[2]) + tt * (sb4.z + (float)B4[2])) * rden;
    o.w = (u * (sa4.w + (float)A4[3]) + tt * (sb4.w + (float)B4[3])) * rden;
    *(float4*)(out + (size_t)slot * (KDIM * WDIM) + (size_t)q * 4) = o;
  }
}

// ======================= FALLBACK: R15 5-kernel path =====================
__global__ __launch_bounds__(256) void k_s12(const float* __restrict__ x,
                                             const float* __restrict__ w,
                                             float* __restrict__ ws, int b0) {
  const int slot = blockIdx.y;
  const int b = b0 + slot;
  float* base = ws + (size_t)slot * PBF;
  __shared__ float w1s[WDIM], w2s[WDIM];
  __shared__ float red1[4][64], red2[4][64];
  int t = threadIdx.x;
  if (t < WDIM) { w1s[t] = w[t]; w2s[t] = w[WDIM + t]; }
  __syncthreads();
  int jj = t & 63, wg = t >> 6;
  int j = blockIdx.x * 64 + jj;
  int w0 = wg * 32;
  const float* xb = x + (size_t)b * (WDIM * KDIM);
  float s1 = 0.f, s2 = 0.f;
  float vals[32];
#pragma unroll
  for (int k = 0; k < 32; ++k) {
    float v = xb[(w0 + k) * KDIM + j];
    vals[k] = v;
    s1 = fmaf(v, w1s[w0 + k], s1);
    s2 = fmaf(v, w2s[w0 + k], s2);
  }
  _Float16* xrowh = (_Float16*)(base + OFF_XTH) + j * WDIM + w0;
#pragma unroll
  for (int q = 0; q < 4; ++q) {
    h8 hv;
#pragma unroll
    for (int e = 0; e < 8; ++e) hv[e] = (_Float16)vals[8 * q + e];
    *(h8*)(xrowh + 8 * q) = hv;
  }
  red1[wg][jj] = s1;
  red2[wg][jj] = s2;
  __syncthreads();
  if (wg == 0) {
    base[OFF_S1 + j] = red1[0][jj] + red1[1][jj] + red1[2][jj] + red1[3][jj];
    base[OFF_S2 + j] = red2[0][jj] + red2[1][jj] + red2[2][jj] + red2[3][jj];
  }
}

__global__ __launch_bounds__(512) void k_rank(float* __restrict__ ws) {
  const int slot = blockIdx.y;
  float* base = ws + (size_t)slot * PBF;
  __shared__ float s2s[KDIM];
  __shared__ float red[512];
  __shared__ int pr[128][4], pc[128][4];
  int t = threadIdx.x;
  for (int i = t; i < KDIM; i += 512) s2s[i] = base[OFF_S2 + i];
  __syncthreads();
  red[t] = fmaxf(s2s[t], s2s[t + 512]);
  __syncthreads();
  for (int s = 256; s > 0; s >>= 1) {
    if (t < s) red[t] = fmaxf(red[t], red[t + s]);
    __syncthreads();
  }
  float M2 = red[0];
  int jj = t >> 2, quarter = t & 3;
  int j = blockIdx.x * 128 + jj;
  float s2me = s2s[j];
  float s1me = base[OFF_S1 + j];
  float key = -s1me;
  int r = 0, c = 0;
  int lo = quarter * 256;
#pragma unroll 4
  for (int k2 = 0; k2 < 256; ++k2) {
    float v = s2s[lo + k2];
    int jp = lo + k2;
    r += (v > s2me || (v == s2me && jp < j)) ? 1 : 0;
    c += (v >= key) ? 1 : 0;
  }
  pr[jj][quarter] = r;
  pc[jj][quarter] = c;
  __syncthreads();
  if (quarter == 0) {
    int R = pr[jj][0] + pr[jj][1] + pr[jj][2] + pr[jj][3];
    int C = pc[jj][0] + pc[jj][1] + pc[jj][2] + pc[jj][3];
    ((int*)(base + OFF_CC))[j] = C;
    ((int*)(base + OFF_PERM))[R] = j;
    base[OFF_ESC + R] = __expf(s2me - M2);
    base[OFF_ESCA + R] = __expf(ALPHA * s2me);
    float z = s1me + M2;
    float mi = z >= 0.f ? z : ALPHA * z;
    base[OFF_U + j] = __expf(z - mi);
    base[OFF_T + j] = __expf(ALPHA * s1me - mi);
  }
}

__global__ __launch_bounds__(128) void k_scant(float* __restrict__ ws) {
  const int slot = blockIdx.y;
  float* base = ws + (size_t)slot * PBF;
  int seg = blockIdx.x;
  int wl = threadIdx.x;
  int r0 = seg * SEGLEN;
  const _Float16* xTh = (const _Float16*)(base + OFF_XTH);
  const int* prm = (const int*)(base + OFF_PERM);
  int pr16[SEGLEN];
#pragma unroll
  for (int k = 0; k < SEGLEN; ++k) pr16[k] = prm[r0 + k];
  float xv[SEGLEN], eav[SEGLEN], ebv[SEGLEN];
#pragma unroll
  for (int k = 0; k < SEGLEN; ++k) {
    xv[k] = (float)xTh[pr16[k] * WDIM + wl];
    eav[k] = base[OFF_ESC + r0 + k];
    ebv[k] = base[OFF_ESCA + r0 + k];
  }
  _Float16* TABh = (_Float16*)(base + OFF_TABH);
  float accA = 0.f;
#pragma unroll
  for (int k = 0; k < SEGLEN; ++k) {
    TABh[(r0 + k) * 256 + wl] = (_Float16)accA;
    accA = fmaf(eav[k], xv[k], accA);
  }
  base[OFF_TA + seg * WDIM + wl] = accA;
  if (seg == NSEG - 1) {
    TABh[KDIM * 256 + wl] = (_Float16)accA;
    TABh[KDIM * 256 + 128 + wl] = (_Float16)0.f;
  }
  float accB = 0.f;
#pragma unroll
  for (int k = SEGLEN - 1; k >= 0; --k) {
    accB = fmaf(ebv[k], xv[k], accB);
    TABh[(r0 + k) * 256 + 128 + wl] = (_Float16)accB;
  }
  base[OFF_TB + seg * WDIM + wl] = accB;
}

__global__ __launch_bounds__(256) void k_base(float* __restrict__ ws) {
  float* base = ws + (size_t)blockIdx.y * PBF;
  __shared__ float gA[2][128], gB[2][128];
  __shared__ float sc[256];
  int t = threadIdx.x;
  if (blockIdx.x == 0) {
    int w = t & 127, h = t >> 7;
    float ta32[32], tb32[32];
    float ga = 0.f, gb = 0.f;
#pragma unroll
    for (int k = 0; k < 32; ++k) {
      ta32[k] = base[OFF_TA + (h * 32 + k) * WDIM + w];
      tb32[k] = base[OFF_TB + (h * 32 + k) * WDIM + w];
      ga += ta32[k];
      gb += tb32[k];
    }
    gA[h][w] = ga;
    gB[h][w] = gb;
    __syncthreads();
    float bA = (h == 1) ? gA[0][w] : 0.f;
    float bB = (h == 0) ? gB[1][w] : 0.f;
#pragma unroll
    for (int k = 0; k < 32; ++k) {
      base[OFF_SBA + (h * 32 + k) * WDIM + w] = bA;
      bA += ta32[k];
    }
#pragma unroll
    for (int k = 31; k >= 0; --k) {
      base[OFF_SBB + (h * 32 + k) * WDIM + w] = bB;
      bB += tb32[k];
    }
  } else if (blockIdx.x == 1) {
    float4 v = *(const float4*)(base + OFF_ESC + 4 * t);
    float p1 = v.x, p2 = p1 + v.y, p3 = p2 + v.z, p4 = p3 + v.w;
    sc[t] = p4;
    __syncthreads();
    for (int s = 1; s < 256; s <<= 1) {
      float add = (t >= s) ? sc[t - s] : 0.f;
      __syncthreads();
      sc[t] += add;
      __syncthreads();
    }
    float bs = (t > 0) ? sc[t - 1] : 0.f;
    float* ABT = base + OFF_ABT;
    ABT[2 * (4 * t + 1)] = bs + p1;
    ABT[2 * (4 * t + 2)] = bs + p2;
    ABT[2 * (4 * t + 3)] = bs + p3;
    ABT[2 * (4 * t + 4)] = bs + p4;
    if (t == 0) ABT[0] = 0.f;
  } else {
    float4 v = *(const float4*)(base + OFF_ESCA + 4 * t);
    float q3 = v.w, q2 = v.z + q3, q1 = v.y + q2, q0 = v.x + q1;
    sc[t] = q0;
    __syncthreads();
    for (int s = 1; s < 256; s <<= 1) {
      float add = (t + s < 256) ? sc[t + s] : 0.f;
      __syncthreads();
      sc[t] += add;
      __syncthreads();
    }
    float bs = (t < 255) ? sc[t + 1] : 0.f;
    float* ABT = base + OFF_ABT;
    ABT[2 * (4 * t + 0) + 1] = bs + q0;
    ABT[2 * (4 * t + 1) + 1] = bs + q1;
    ABT[2 * (4 * t + 2) + 1] = bs + q2;
    ABT[2 * (4 * t + 3) + 1] = bs + q3;
    if (t == 255) ABT[2 * KDIM + 1] = 0.f;
  }
}

__global__ __launch_bounds__(256) void k_out(const float* __restrict__ ws,
                                             float* __restrict__ out, int b0) {
  const int slot = blockIdx.y;
  const int b = b0 + slot;
  const float* base = ws + (size_t)slot * PBF;
  int q = blockIdx.x * 256 + threadIdx.x;
  int i = q >> 5;
  int wq = (q & 31) << 2;
  int c = ((const int*)(base + OFF_CC))[i];
  int seg = c >> 4; if (seg > NSEG - 1) seg = NSEG - 1;
  float u = base[OFF_U + i];
  float tt = base[OFF_T + i];
  float2 ab = *(const float2*)(base + OFF_ABT + 2 * c);
  float rden = 1.f / fmaf(u, ab.x, tt * ab.y);
  const _Float16* TABh = (const _Float16*)(base + OFF_TABH);
  h4 A4 = *(const h4*)(TABh + (size_t)c * 256 + wq);
  h4 B4 = *(const h4*)(TABh + (size_t)c * 256 + 128 + wq);
  float4 sa4 = *(const float4*)(base + OFF_SBA + seg * WDIM + wq);
  float4 sb4 = *(const float4*)(base + OFF_SBB + seg * WDIM + wq);
  float4 o;
  o.x = (u * (sa4.x + (float)A4[0]) + tt * (sb4.x + (float)B4[0])) * rden;
  o.y = (u * (sa4.y + (float)A4[1]) + tt * (sb4.y + (float)B4[1])) * rden;
  o.z = (u * (sa4.z + (float)A4[2]) + tt * (sb4.z + (float)B4[2])) * rden;
  o.w = (u * (sa4.w + (float)A4[3]) + tt * (sb4.w + (float)B4[3])) * rden;
  *(float4*)(out + (size_t)b * (KDIM * WDIM) + (size_t)q * 4) = o;
}

extern "C" void kernel_launch(void* const* d_in, const int* in_sizes, int n_in,
                              void* d_out, int out_size, void* d_ws, size_t ws_size,
                              hipStream_t stream) {
  const float* x = (const float*)d_in[0];
  const float* w = (const float*)d_in[1];
  float* out = (float*)d_out;
  float* ws = (float*)d_ws;

  bool use_mega = (ws_size >= (size_t)PBF * NB * sizeof(float));
  if (use_mega) {
    int dev = 0;
    if (hipGetDevice(&dev) != hipSuccess) use_mega = false;
    int coop = 0;
    if (use_mega &&
        hipDeviceGetAttribute(&coop, hipDeviceAttributeCooperativeLaunch, dev) != hipSuccess)
      use_mega = false;
    if (coop == 0) use_mega = false;
  }
  if (use_mega) {
    const float* xa = x; const float* wa = w; float* wsa = ws; float* outa = out;
    void* args[4] = {&xa, &wa, &wsa, &outa};
    hipError_t err = hipLaunchCooperativeKernel((const void*)k_mega, dim3(512),
                                                dim3(256), args, 0, stream);
    if (err == hipSuccess) return;
  }
  // fallback: R15 5-kernel path
  size_t perb = (size_t)PBF * sizeof(float);
  int nbmax = (int)(ws_size / perb);
  if (nbmax < 1) nbmax = 1;
  if (nbmax > NB) nbmax = NB;
  for (int b0 = 0; b0 < NB; b0 += nbmax) {
    int nb = (NB - b0 < nbmax) ? (NB - b0) : nbmax;
    k_s12<<<dim3(16, nb), 256, 0, stream>>>(x, w, ws, b0);
    k_rank<<<dim3(8, nb), 512, 0, stream>>>(ws);
    k_scant<<<dim3(NSEG, nb), 128, 0, stream>>>(ws);
    k_base<<<dim3(3, nb), 256, 0, stream>>>(ws);
    k_out<<<dim3(128, nb), 256, 0, stream>>>(ws, out, b0);
  }
}

// Round 17
// 44.208 us; speedup vs baseline: 6.7757x; 6.7757x over previous
//
#include <hip/hip_runtime.h>

#define ALPHA 0.2f

constexpr int WDIM = 128;
constexpr int KDIM = 1024;
constexpr int NSEG = 64;             // rank segments
constexpr int SEGLEN = KDIM / NSEG;  // 16

typedef _Float16 h4 __attribute__((ext_vector_type(4)));
typedef _Float16 h8 __attribute__((ext_vector_type(8)));

// per-batch workspace layout (float offsets). XTH = 1024*128 fp16 = 65536
// floats. All regions disjoint (the R6-R13 overlap race is fixed here).
constexpr int OFF_XTH  = 0;        // [1024][128] _Float16 xT (65536 floats)
constexpr int OFF_TABH = 65536;    // [1025][256] _Float16 within-seg partials (131200 fl)
constexpr int OFF_ESC  = 196736;   // [1024] f32 exp(s2 - M2) sorted desc
constexpr int OFF_ESCA = 197760;   // [1024] f32 exp(alpha*s2) sorted
constexpr int OFF_ABT  = 198784;   // [1025][2] f32 (a(c), b(c)) pad->2176
constexpr int OFF_U    = 200960;   // [1024]
constexpr int OFF_T    = 201984;   // [1024]
constexpr int OFF_S1   = 203008;   // [1024]
constexpr int OFF_S2   = 204032;   // [1024]
constexpr int OFF_CC   = 205056;   // [1024] int: c_i
constexpr int OFF_PERM = 206080;   // [1024] int: perm[rank] = j
constexpr int OFF_TA   = 207104;   // [NSEG][128] segment totals (A)
constexpr int OFF_TB   = 215296;   // [NSEG][128] segment totals (B)
constexpr int OFF_SBA  = 223488;   // [NSEG][128] f32 base: sum of segs before
constexpr int OFF_SBB  = 231680;   // [NSEG][128] f32 base: sum of segs after
constexpr int PBF      = 239872;   // per-batch stride (floats) = 959 KB

// K1: s1, s2, transpose x -> xT (fp16). grid (16, nb) x 256
__global__ __launch_bounds__(256) void k_s12(const float* __restrict__ x,
                                             const float* __restrict__ w,
                                             float* __restrict__ ws, int b0) {
  const int slot = blockIdx.y;
  const int b = b0 + slot;
  float* base = ws + (size_t)slot * PBF;
  __shared__ float w1s[WDIM], w2s[WDIM];
  __shared__ float red1[4][64], red2[4][64];
  int t = threadIdx.x;
  if (t < WDIM) { w1s[t] = w[t]; w2s[t] = w[WDIM + t]; }
  __syncthreads();
  int jj = t & 63, wg = t >> 6;
  int j = blockIdx.x * 64 + jj;
  int w0 = wg * 32;
  const float* xb = x + (size_t)b * (WDIM * KDIM);
  float s1 = 0.f, s2 = 0.f;
  float vals[32];
#pragma unroll
  for (int k = 0; k < 32; ++k) {
    float v = xb[(w0 + k) * KDIM + j];
    vals[k] = v;
    s1 = fmaf(v, w1s[w0 + k], s1);
    s2 = fmaf(v, w2s[w0 + k], s2);
  }
  _Float16* xrowh = (_Float16*)(base + OFF_XTH) + j * WDIM + w0;
#pragma unroll
  for (int q = 0; q < 4; ++q) {
    h8 hv;
#pragma unroll
    for (int e = 0; e < 8; ++e) hv[e] = (_Float16)vals[8 * q + e];
    *(h8*)(xrowh + 8 * q) = hv;
  }
  red1[wg][jj] = s1;
  red2[wg][jj] = s2;
  __syncthreads();
  if (wg == 0) {
    base[OFF_S1 + j] = red1[0][jj] + red1[1][jj] + red1[2][jj] + red1[3][jj];
    base[OFF_S2 + j] = red2[0][jj] + red2[1][jj] + red2[2][jj] + red2[3][jj];
  }
}

// K2: rank/count/scatter. grid (8, nb) x 512
__global__ __launch_bounds__(512) void k_rank(float* __restrict__ ws) {
  const int slot = blockIdx.y;
  float* base = ws + (size_t)slot * PBF;
  __shared__ float s2s[KDIM];
  __shared__ float red[512];
  __shared__ int pr[128][4], pc[128][4];
  int t = threadIdx.x;
  for (int i = t; i < KDIM; i += 512) s2s[i] = base[OFF_S2 + i];
  __syncthreads();
  red[t] = fmaxf(s2s[t], s2s[t + 512]);
  __syncthreads();
  for (int s = 256; s > 0; s >>= 1) {
    if (t < s) red[t] = fmaxf(red[t], red[t + s]);
    __syncthreads();
  }
  float M2 = red[0];
  int jj = t >> 2, quarter = t & 3;
  int j = blockIdx.x * 128 + jj;
  float s2me = s2s[j];
  float s1me = base[OFF_S1 + j];
  float key = -s1me;
  int r = 0, c = 0;
  int lo = quarter * 256;
#pragma unroll 4
  for (int k2 = 0; k2 < 256; ++k2) {
    float v = s2s[lo + k2];
    int jp = lo + k2;
    r += (v > s2me || (v == s2me && jp < j)) ? 1 : 0;
    c += (v >= key) ? 1 : 0;
  }
  pr[jj][quarter] = r;
  pc[jj][quarter] = c;
  __syncthreads();
  if (quarter == 0) {
    int R = pr[jj][0] + pr[jj][1] + pr[jj][2] + pr[jj][3];
    int C = pc[jj][0] + pc[jj][1] + pc[jj][2] + pc[jj][3];
    ((int*)(base + OFF_CC))[j] = C;
    ((int*)(base + OFF_PERM))[R] = j;
    base[OFF_ESC + R] = __expf(s2me - M2);
    base[OFF_ESCA + R] = __expf(ALPHA * s2me);
    float z = s1me + M2;
    float mi = z >= 0.f ? z : ALPHA * z;
    base[OFF_U + j] = __expf(z - mi);
    base[OFF_T + j] = __expf(ALPHA * s1me - mi);
  }
}

// K3: within-seg partial scans -> TAB (fp16, seg-relative) + seg totals.
// grid (NSEG, nb) x 128
__global__ __launch_bounds__(128) void k_scant(float* __restrict__ ws) {
  const int slot = blockIdx.y;
  float* base = ws + (size_t)slot * PBF;
  int seg = blockIdx.x;
  int wl = threadIdx.x;
  int r0 = seg * SEGLEN;
  const _Float16* xTh = (const _Float16*)(base + OFF_XTH);
  const int* prm = (const int*)(base + OFF_PERM);
  int pr16[SEGLEN];
#pragma unroll
  for (int k = 0; k < SEGLEN; ++k) pr16[k] = prm[r0 + k];
  float xv[SEGLEN], eav[SEGLEN], ebv[SEGLEN];
#pragma unroll
  for (int k = 0; k < SEGLEN; ++k) {
    xv[k] = (float)xTh[pr16[k] * WDIM + wl];
    eav[k] = base[OFF_ESC + r0 + k];
    ebv[k] = base[OFF_ESCA + r0 + k];
  }
  _Float16* TABh = (_Float16*)(base + OFF_TABH);
  float accA = 0.f;
#pragma unroll
  for (int k = 0; k < SEGLEN; ++k) {
    TABh[(r0 + k) * 256 + wl] = (_Float16)accA;
    accA = fmaf(eav[k], xv[k], accA);
  }
  base[OFF_TA + seg * WDIM + wl] = accA;            // seg total (A)
  if (seg == NSEG - 1) {
    TABh[KDIM * 256 + wl] = (_Float16)accA;
    TABh[KDIM * 256 + 128 + wl] = (_Float16)0.f;
  }
  float accB = 0.f;
#pragma unroll
  for (int k = SEGLEN - 1; k >= 0; --k) {
    accB = fmaf(ebv[k], xv[k], accB);
    TABh[(r0 + k) * 256 + 128 + wl] = (_Float16)accB;
  }
  base[OFF_TB + seg * WDIM + wl] = accB;            // seg total (B)
}

// K4: grid (3, nb) x 256. bx=0: SBA/SBB. bx=1: scalar prefix a(c).
// bx=2: scalar suffix b(c).
__global__ __launch_bounds__(256) void k_base(float* __restrict__ ws) {
  float* base = ws + (size_t)blockIdx.y * PBF;
  __shared__ float gA[2][128], gB[2][128];
  __shared__ float sc[256];
  int t = threadIdx.x;
  if (blockIdx.x == 0) {
    int w = t & 127, h = t >> 7;
    float ta32[32], tb32[32];
    float ga = 0.f, gb = 0.f;
#pragma unroll
    for (int k = 0; k < 32; ++k) {
      ta32[k] = base[OFF_TA + (h * 32 + k) * WDIM + w];
      tb32[k] = base[OFF_TB + (h * 32 + k) * WDIM + w];
      ga += ta32[k];
      gb += tb32[k];
    }
    gA[h][w] = ga;
    gB[h][w] = gb;
    __syncthreads();
    float bA = (h == 1) ? gA[0][w] : 0.f;
    float bB = (h == 0) ? gB[1][w] : 0.f;
#pragma unroll
    for (int k = 0; k < 32; ++k) {
      base[OFF_SBA + (h * 32 + k) * WDIM + w] = bA;
      bA += ta32[k];
    }
#pragma unroll
    for (int k = 31; k >= 0; --k) {
      base[OFF_SBB + (h * 32 + k) * WDIM + w] = bB;
      bB += tb32[k];
    }
  } else if (blockIdx.x == 1) {
    // prefix scan of ESC -> a(c) = sum_{r<c} esc[r], c in 0..1024
    float4 v = *(const float4*)(base + OFF_ESC + 4 * t);
    float p1 = v.x, p2 = p1 + v.y, p3 = p2 + v.z, p4 = p3 + v.w;
    sc[t] = p4;
    __syncthreads();
    for (int s = 1; s < 256; s <<= 1) {
      float add = (t >= s) ? sc[t - s] : 0.f;
      __syncthreads();
      sc[t] += add;
      __syncthreads();
    }
    float bs = (t > 0) ? sc[t - 1] : 0.f;
    float* ABT = base + OFF_ABT;
    ABT[2 * (4 * t + 1)] = bs + p1;
    ABT[2 * (4 * t + 2)] = bs + p2;
    ABT[2 * (4 * t + 3)] = bs + p3;
    ABT[2 * (4 * t + 4)] = bs + p4;
    if (t == 0) ABT[0] = 0.f;
  } else {
    // suffix scan of ESCA -> b(c) = sum_{r>=c} esca[r], c in 0..1024
    float4 v = *(const float4*)(base + OFF_ESCA + 4 * t);
    float q3 = v.w, q2 = v.z + q3, q1 = v.y + q2, q0 = v.x + q1;
    sc[t] = q0;
    __syncthreads();
    for (int s = 1; s < 256; s <<= 1) {
      float add = (t + s < 256) ? sc[t + s] : 0.f;
      __syncthreads();
      sc[t] += add;
      __syncthreads();
    }
    float bs = (t < 255) ? sc[t + 1] : 0.f;
    float* ABT = base + OFF_ABT;
    ABT[2 * (4 * t + 0) + 1] = bs + q0;
    ABT[2 * (4 * t + 1) + 1] = bs + q1;
    ABT[2 * (4 * t + 2) + 1] = bs + q2;
    ABT[2 * (4 * t + 3) + 1] = bs + q3;
    if (t == 255) ABT[2 * KDIM + 1] = 0.f;
  }
}

// K5: h_i = (u*(SBA+partA) + t*(SBB+partB)) / (u*a + t*b). grid (128, nb) x 256
__global__ __launch_bounds__(256) void k_out(const float* __restrict__ ws,
                                             float* __restrict__ out, int b0) {
  const int slot = blockIdx.y;
  const int b = b0 + slot;
  const float* base = ws + (size_t)slot * PBF;
  int q = blockIdx.x * 256 + threadIdx.x;  // 0..32767
  int i = q >> 5;
  int wq = (q & 31) << 2;
  int c = ((const int*)(base + OFF_CC))[i];
  int seg = c >> 4; if (seg > NSEG - 1) seg = NSEG - 1;  // c=1024 -> seg 63
  float u = base[OFF_U + i];
  float tt = base[OFF_T + i];
  float2 ab = *(const float2*)(base + OFF_ABT + 2 * c);
  float rden = 1.f / fmaf(u, ab.x, tt * ab.y);
  const _Float16* TABh = (const _Float16*)(base + OFF_TABH);
  h4 A4 = *(const h4*)(TABh + (size_t)c * 256 + wq);
  h4 B4 = *(const h4*)(TABh + (size_t)c * 256 + 128 + wq);
  float4 sa4 = *(const float4*)(base + OFF_SBA + seg * WDIM + wq);
  float4 sb4 = *(const float4*)(base + OFF_SBB + seg * WDIM + wq);
  float4 o;
  o.x = (u * (sa4.x + (float)A4[0]) + tt * (sb4.x + (float)B4[0])) * rden;
  o.y = (u * (sa4.y + (float)A4[1]) + tt * (sb4.y + (float)B4[1])) * rden;
  o.z = (u * (sa4.z + (float)A4[2]) + tt * (sb4.z + (float)B4[2])) * rden;
  o.w = (u * (sa4.w + (float)A4[3]) + tt * (sb4.w + (float)B4[3])) * rden;
  *(float4*)(out + (size_t)b * (KDIM * WDIM) + (size_t)q * 4) = o;
}

extern "C" void kernel_launch(void* const* d_in, const int* in_sizes, int n_in,
                              void* d_out, int out_size, void* d_ws, size_t ws_size,
                              hipStream_t stream) {
  const float* x = (const float*)d_in[0];
  const float* w = (const float*)d_in[1];
  float* out = (float*)d_out;
  float* ws = (float*)d_ws;
  const int NB = 32;
  size_t perb = (size_t)PBF * sizeof(float);
  int nbmax = (int)(ws_size / perb);
  if (nbmax < 1) nbmax = 1;
  if (nbmax > NB) nbmax = NB;
  for (int b0 = 0; b0 < NB; b0 += nbmax) {
    int nb = (NB - b0 < nbmax) ? (NB - b0) : nbmax;
    k_s12<<<dim3(16, nb), 256, 0, stream>>>(x, w, ws, b0);
    k_rank<<<dim3(8, nb), 512, 0, stream>>>(ws);
    k_scant<<<dim3(NSEG, nb), 128, 0, stream>>>(ws);
    k_base<<<dim3(3, nb), 256, 0, stream>>>(ws);
    k_out<<<dim3(128, nb), 256, 0, stream>>>(ws, out, b0);
  }
}